// Round 1
// baseline (182.501 us; speedup 1.0000x reference)
//
#include <hip/hip_runtime.h>

typedef __attribute__((ext_vector_type(8))) short short8;
typedef __attribute__((ext_vector_type(4))) float f32x4;
typedef __attribute__((ext_vector_type(4))) unsigned int u32x4;

#define NTOK 4096
#define DIM  256
#define P_STRIDE 72        // P row stride elems (144 B); chunk kc at pos = kc ^ (2*((r>>3)&1))
#define TILE_ELEMS 32768   // ushort elems per 64KB tile image (Ks 16384 | Kt 16384)

__device__ __forceinline__ unsigned pack2bf(float a, float b) {
  unsigned ua = __builtin_bit_cast(unsigned, a) + 0x8000u;
  unsigned ub = __builtin_bit_cast(unsigned, b) + 0x8000u;
  return __builtin_amdgcn_perm(ub, ua, 0x07060302u); // low=bf16(a), high=bf16(b)
}

// ---- prologue: per-tile bf16 images (unchanged) --------------------------
// Img[b][t] = [ Ks: 64 rows x 32 chunks(16B), chunk c at (c ^ (r&7))
//             | Kt: 8 kb-blocks x 256 d x 8 tokens ]
__global__ __launch_bounds__(256, 4)
void prep_kernel(const float* __restrict__ X, unsigned short* __restrict__ Img) {
  const int b    = blockIdx.x & 3;
  const int sub  = blockIdx.x >> 2;   // 0..511
  const int t    = sub >> 3;
  const int part = sub & 7;
  const int tid  = threadIdx.x;
  const float* src = X + ((size_t)b * NTOK + t * 64) * DIM;
  unsigned short* dst = Img + ((size_t)(b * 64 + t)) * TILE_ELEMS;
  {
    int r = part * 8 + (tid >> 5);
    int c = tid & 31;
    const float* s = src + r * DIM + c * 8;
    f32x4 f0 = *(const f32x4*)s;
    f32x4 f1 = *(const f32x4*)(s + 4);
    union { unsigned u[4]; u32x4 v; } p;
    p.u[0] = pack2bf(f0[0], f0[1]);
    p.u[1] = pack2bf(f0[2], f0[3]);
    p.u[2] = pack2bf(f1[0], f1[1]);
    p.u[3] = pack2bf(f1[2], f1[3]);
    *(u32x4*)(dst + r * 256 + ((c ^ (r & 7)) << 3)) = p.v;
  }
  {
    const int d = tid;
    float f[8];
    #pragma unroll
    for (int i = 0; i < 8; ++i) f[i] = src[(part * 8 + i) * DIM + d];
    union { unsigned u[4]; u32x4 v; } p;
    p.u[0] = pack2bf(f[0], f[1]);
    p.u[1] = pack2bf(f[2], f[3]);
    p.u[2] = pack2bf(f[4], f[5]);
    p.u[3] = pack2bf(f[6], f[7]);
    *(u32x4*)(dst + 16384 + part * 2048 + d * 8) = p.v;
  }
}

// ---- flash-attention: 32-row q-tiles, 512 blocks, 2 blocks/CU ------------
// QK decomposition: wave -> (qh = wave&1: q-strip of 16 rows, role = wave>>1: 16 keys)
// PV decomposition: wave -> d-slice [wave*32, wave*32+32), both strips, all 64 keys
// Kt is NOT staged in LDS: PV B-fragments come straight from Img (L2-resident),
// register-double-buffered across iterations (bvN loaded at t, used at t+1).
__global__ __launch_bounds__(512, 4)
void fa_kernel(const unsigned short* __restrict__ Img, float* __restrict__ Out) {
  __shared__ __align__(16) unsigned short ksb[2][16384];        // 64 KB (Ks dbuf)
  __shared__ __align__(16) unsigned short pb[2][32 * P_STRIDE]; //  9 KB (P dbuf)
  __shared__ __align__(16) float lbuf[32][4];                   // 0.5 KB

  const int tid  = threadIdx.x;
  const int bid  = blockIdx.x;
  // XCD grouping: default round-robin maps bid%8 -> XCD; give each XCD pair one batch b
  const int b    = (bid & 7) >> 1;                 // 0..3
  const int qblk = ((bid >> 3) << 1) | (bid & 1);  // 0..127 (32-row q tiles)
  const int wave = tid >> 6;
  const int lane = tid & 63;
  const int ln   = lane & 15;
  const int quad = lane >> 4;
  const int swz  = ln & 7;
  const int qh   = wave & 1;   // QK: q strip
  const int role = wave >> 1;  // QK: key-16 group

  const unsigned short* imgb  = Img + (size_t)b * 64 * TILE_ELEMS;
  const char*           imgbc = (const char*)imgb;

  // Q fragments for this wave's strip: rows qblk*32 + qh*16 + ln
  short8 aQ[8];
  {
    const unsigned short* qrow =
        imgb + (size_t)(qblk >> 1) * TILE_ELEMS + ((qblk & 1) * 32 + qh * 16 + ln) * 256;
    #pragma unroll
    for (int ds = 0; ds < 8; ++ds)
      aQ[ds] = *(const short8*)(qrow + (((ds * 4 + quad) ^ swz) << 3));
  }

  f32x4 o[2][2];
  #pragma unroll
  for (int s = 0; s < 2; ++s)
    #pragma unroll
    for (int dt = 0; dt < 2; ++dt) o[s][dt] = (f32x4)(0.0f);
  float lrow[4] = {0.f, 0.f, 0.f, 0.f};

  const float c2 = 0.0901684400f;  // log2(e)/sqrt(256)

  // P write constants: kc = role*2 + (ln>>3); pos = kc ^ (2*(quad>>1))
  const int pwPos = ((role * 2 + (ln >> 3)) ^ ((quad >> 1) << 1)) << 3;
  const int pwCol = ln & 7;

  // Ks DMA: all 8 waves, 4 x 1KB each = 32KB
  const char* gK = imgbc + (size_t)wave * 4096 + (size_t)lane * 16;
  #pragma unroll
  for (int i = 0; i < 4; ++i)
    __builtin_amdgcn_global_load_lds(
        (const __attribute__((address_space(1))) unsigned*)(gK + i * 1024),
        (__attribute__((address_space(3))) unsigned*)(&ksb[0][wave * 2048 + i * 512]),
        16, 0, 0);

  // PV B-fragment base in Kt image: kb = ks*4+quad, d = wave*32 + dt*16 + ln
  const unsigned short* ktbase = imgb + 16384 + (size_t)quad * 2048 + (wave * 32 + ln) * 8;

  short8 bvA[2][2];  // Kt(t-1), consumed by PV(t-1) in iter t
  short8 bvN[2][2];  // Kt(t), loaded in iter t

  for (int t = 0; t < 64; ++t) {
    __syncthreads();  // drains last iter's DMA + bv loads; P(t-1)/Ks(t) ready
    const int buf = t & 1;

    // issue Ks(t+1) DMA
    if (t < 63) {
      const char* g = gK + (size_t)(t + 1) * 65536;
      unsigned short* l = &ksb[buf ^ 1][wave * 2048];
      #pragma unroll
      for (int i = 0; i < 4; ++i)
        __builtin_amdgcn_global_load_lds(
            (const __attribute__((address_space(1))) unsigned*)(g + i * 1024),
            (__attribute__((address_space(3))) unsigned*)(l + i * 512),
            16, 0, 0);
    }

    // issue Kt(t) loads (used by PV(t) next iter — a full iteration to land)
    {
      const unsigned short* kt = ktbase + (size_t)t * TILE_ELEMS;
      #pragma unroll
      for (int ks = 0; ks < 2; ++ks)
        #pragma unroll
        for (int dt = 0; dt < 2; ++dt)
          bvN[ks][dt] = *(const short8*)(kt + ks * 8192 + dt * 128);
    }

    // --- QK(t): this wave's strip x its 16 keys ---
    f32x4 sf = (f32x4)(0.0f);
    {
      const unsigned short* krow = &ksb[buf][(role * 16 + ln) * 256];
      #pragma unroll
      for (int ds = 0; ds < 8; ++ds) {
        short8 bk = *(const short8*)(krow + (((ds * 4 + quad) ^ swz) << 3));
        sf = __builtin_amdgcn_mfma_f32_16x16x32_bf16(aQ[ds], bk, sf, 0, 0, 0);
      }
    }

    // --- softmax numerators; packed conflict-free P store ---
    {
      unsigned short* pw = pb[buf];
      #pragma unroll
      for (int j = 0; j < 4; ++j) {
        float p0 = __builtin_amdgcn_exp2f(sf[j] * c2);
        lrow[j] += p0;
        unsigned q0 = __builtin_bit_cast(unsigned, p0);
        // partner (lane^1) via DPP quad_perm [1,0,3,2] = 0xB1 (pure VALU)
        unsigned n0 = (unsigned)__builtin_amdgcn_mov_dpp((int)q0, 0xB1, 0xF, 0xF, true);
        if ((ln & 1) == 0) {
          const int r0 = qh * 16 + quad * 4 + j;
          unsigned d0 = pack2bf(__builtin_bit_cast(float, q0), __builtin_bit_cast(float, n0));
          *(unsigned*)(&pw[r0 * P_STRIDE + pwPos + pwCol]) = d0;
        }
      }
    }

    // --- PV(t-1): this wave's 32-wide d-slice, both strips, all 64 keys ---
    if (t > 0) {
      const unsigned short* pr = pb[buf ^ 1];
      #pragma unroll
      for (int ks = 0; ks < 2; ++ks) {
        const int pos = (ks * 4 + quad) ^ ((ln >> 3) << 1);
        short8 ap[2];
        #pragma unroll
        for (int s = 0; s < 2; ++s)
          ap[s] = *(const short8*)(&pr[(s * 16 + ln) * P_STRIDE + (pos << 3)]);
        #pragma unroll
        for (int s = 0; s < 2; ++s)
          #pragma unroll
          for (int dt = 0; dt < 2; ++dt)
            o[s][dt] = __builtin_amdgcn_mfma_f32_16x16x32_bf16(ap[s], bvA[ks][dt], o[s][dt], 0, 0, 0);
      }
    }

    // rotate register double-buffer
    #pragma unroll
    for (int ks = 0; ks < 2; ++ks)
      #pragma unroll
      for (int dt = 0; dt < 2; ++dt) bvA[ks][dt] = bvN[ks][dt];
  }

  __syncthreads();  // P(63) resident
  // final PV(63): pb[1], bvA = Kt(63)
  {
    const unsigned short* pr = pb[1];
    #pragma unroll
    for (int ks = 0; ks < 2; ++ks) {
      const int pos = (ks * 4 + quad) ^ ((ln >> 3) << 1);
      short8 ap[2];
      #pragma unroll
      for (int s = 0; s < 2; ++s)
        ap[s] = *(const short8*)(&pr[(s * 16 + ln) * P_STRIDE + (pos << 3)]);
      #pragma unroll
      for (int s = 0; s < 2; ++s)
        #pragma unroll
        for (int dt = 0; dt < 2; ++dt)
          o[s][dt] = __builtin_amdgcn_mfma_f32_16x16x32_bf16(ap[s], bvA[ks][dt], o[s][dt], 0, 0, 0);
    }
  }

  // --- merge l across the 4 roles, divide, store ---
  #pragma unroll
  for (int off = 1; off < 16; off <<= 1)
    #pragma unroll
    for (int j = 0; j < 4; ++j)
      lrow[j] += __shfl_xor(lrow[j], off, 64);
  if (ln == 0) {
    #pragma unroll
    for (int j = 0; j < 4; ++j)
      lbuf[qh * 16 + quad * 4 + j][role] = lrow[j];
  }
  __syncthreads();

  #pragma unroll
  for (int s = 0; s < 2; ++s) {
    float* outp = Out + (size_t)(b * NTOK + qblk * 32 + s * 16) * DIM + wave * 32;
    #pragma unroll
    for (int j = 0; j < 4; ++j) {
      const int row = quad * 4 + j;
      f32x4 lv = *(const f32x4*)lbuf[s * 16 + row];
      const float rl = 1.0f / (lv[0] + lv[1] + lv[2] + lv[3]);
      #pragma unroll
      for (int dt = 0; dt < 2; ++dt)
        outp[(size_t)row * DIM + dt * 16 + ln] = o[s][dt][j] * rl;
    }
  }
}

extern "C" void kernel_launch(void* const* d_in, const int* in_sizes, int n_in,
                              void* d_out, int out_size, void* d_ws, size_t ws_size,
                              hipStream_t stream) {
  const float* X = (const float*)d_in[0];       // x: fp32 [4,4096,256]
  float* Out = (float*)d_out;                   // fp32 [4,4096,256]
  unsigned short* Img = (unsigned short*)d_ws;  // 16 MB bf16 tile images
  (void)in_sizes; (void)n_in; (void)out_size; (void)ws_size;
  hipLaunchKernelGGL(prep_kernel, dim3(2048), dim3(256), 0, stream, X, Img);
  hipLaunchKernelGGL(fa_kernel, dim3(512), dim3(512), 0, stream, Img, Out);
}